// Round 1
// baseline (817.458 us; speedup 1.0000x reference)
//
#include <hip/hip_runtime.h>
#include <math.h>

// ---------------------------------------------------------------------------
// AttentionCl fused block, fp32 baseline (no MFMA: CDNA4 has no fp32 MFMA).
//   K1: qkv_gemm  : x[8192,512] @ Wqkv[512,1536] + b  -> scatter Q,K,V [B,H,N,32]
//       (softmax scale 1/sqrt(32) folded into Q at scatter time)
//   K2: attn      : flash-style online softmax, bias = rel[h,n,m], out [B,N,H*32]
//   K3: proj_gemm : aout[8192,512] @ Wproj[512,512] + b -> d_out
// Workspace: 3 x 16MB (QKV) + 16MB (attn out) = 64MB fp32.
// ---------------------------------------------------------------------------

constexpr int kB  = 8;
constexpr int kNH = 16;
constexpr int kDH = 32;
constexpr int kC  = 512;
constexpr int kN  = 1024;          // H*W
constexpr int kBN = kB * kN;       // 8192
constexpr int kQKV = 3 * kNH * kDH; // 1536

// ---------------- K1: QKV projection GEMM + scatter ------------------------
// 64x64 tile, K-chunk 32, 256 threads, 4x4 micro-tile.
__global__ __launch_bounds__(256) void qkv_gemm(
    const float* __restrict__ A,      // x [8192,512]
    const float* __restrict__ Bw,     // W_qkv [512,1536]
    const float* __restrict__ bias,   // [1536]
    float* __restrict__ q_ws, float* __restrict__ k_ws, float* __restrict__ v_ws)
{
    __shared__ float As[32][64];      // A^T tile: As[k][m]
    __shared__ float Bs[32][64];      // Bs[k][n]
    const int tid = threadIdx.x;
    const int tx = tid & 15, ty = tid >> 4;
    const int m0 = blockIdx.x * 64;
    const int n0 = blockIdx.y * 64;

    float acc[4][4] = {};
    for (int k0 = 0; k0 < kC; k0 += 32) {
        int i = tid;
        #pragma unroll
        for (int rep = 0; rep < 2; rep++, i += 256) {   // A tile: 512 float4
            int r = i >> 3, c4 = (i & 7) * 4;
            float4 v = *reinterpret_cast<const float4*>(A + (size_t)(m0 + r) * kC + k0 + c4);
            As[c4 + 0][r] = v.x;
            As[c4 + 1][r] = v.y;
            As[c4 + 2][r] = v.z;
            As[c4 + 3][r] = v.w;
        }
        i = tid;
        #pragma unroll
        for (int rep = 0; rep < 2; rep++, i += 256) {   // B tile: 512 float4
            int r = i >> 4, c4 = (i & 15) * 4;
            *reinterpret_cast<float4*>(&Bs[r][c4]) =
                *reinterpret_cast<const float4*>(Bw + (size_t)(k0 + r) * kQKV + n0 + c4);
        }
        __syncthreads();
        #pragma unroll
        for (int k = 0; k < 32; k++) {
            float a[4], b[4];
            *reinterpret_cast<float4*>(a) = *reinterpret_cast<const float4*>(&As[k][ty * 4]);
            *reinterpret_cast<float4*>(b) = *reinterpret_cast<const float4*>(&Bs[k][tx * 4]);
            #pragma unroll
            for (int ii = 0; ii < 4; ii++)
                #pragma unroll
                for (int jj = 0; jj < 4; jj++)
                    acc[ii][jj] = fmaf(a[ii], b[jj], acc[ii][jj]);
        }
        __syncthreads();
    }

    // Epilogue: bias + scatter. Columns group as head = col/96, r = col%96,
    // r<32 -> Q, <64 -> K, else V. 4-col groups never straddle a boundary
    // (all boundaries are multiples of 4), so float4 stores are safe.
    const float scale = 0.17677669529663687f;   // 1/sqrt(32), folded into Q
    const int col0 = n0 + tx * 4;
    const int head = col0 / 96;
    const int r = col0 - head * 96;
    const float4 bv = *reinterpret_cast<const float4*>(bias + col0);
    #pragma unroll
    for (int ii = 0; ii < 4; ii++) {
        const int m = m0 + ty * 4 + ii;
        const int bb = m >> 10, n = m & 1023;
        float4 v;
        v.x = acc[ii][0] + bv.x;
        v.y = acc[ii][1] + bv.y;
        v.z = acc[ii][2] + bv.z;
        v.w = acc[ii][3] + bv.w;
        const size_t base = ((size_t)(bb * kNH + head) * kN + n) * kDH;
        if (r < 32) {
            v.x *= scale; v.y *= scale; v.z *= scale; v.w *= scale;
            *reinterpret_cast<float4*>(q_ws + base + r) = v;
        } else if (r < 64) {
            *reinterpret_cast<float4*>(k_ws + base + (r - 32)) = v;
        } else {
            *reinterpret_cast<float4*>(v_ws + base + (r - 64)) = v;
        }
    }
}

// ---------------- K2: flash-style attention --------------------------------
// grid (N/32, B*NH), 256 threads. Wave: 4 row-pairs x 16 subs; each lane owns
// 2 query rows and the m-slice {sub + 16*i}. LDS rows padded to 36 floats:
// bank(lane) = 4*sub mod 32 -> 2-way conflict (free), rows stay 16B-aligned.
__global__ __launch_bounds__(256) void attn_kernel(
    const float* __restrict__ q_ws, const float* __restrict__ k_ws,
    const float* __restrict__ v_ws, const float* __restrict__ rel,
    float* __restrict__ aout)    // [8192, 512] = [B*N, heads*dh]
{
    __shared__ float Ks[128][36];
    __shared__ float Vs[128][36];
    const int tid = threadIdx.x;
    const int wave = tid >> 6;
    const int lane = tid & 63;
    const int pair = lane >> 4;     // 0..3 -> row pair within wave
    const int sub  = lane & 15;     // 0..15 -> m-slice
    const int bh = blockIdx.y;
    const int bb = bh >> 4, h = bh & 15;
    const int r0 = blockIdx.x * 32 + wave * 8 + pair * 2;   // rows r0, r0+1

    float q0[32], q1[32];
    const float* qp = q_ws + ((size_t)bh * kN + r0) * kDH;
    #pragma unroll
    for (int d4 = 0; d4 < 8; d4++) {
        *reinterpret_cast<float4*>(&q0[d4 * 4]) = *reinterpret_cast<const float4*>(qp + d4 * 4);
        *reinterpret_cast<float4*>(&q1[d4 * 4]) = *reinterpret_cast<const float4*>(qp + kDH + d4 * 4);
    }

    float acc0[32], acc1[32];
    #pragma unroll
    for (int d = 0; d < 32; d++) { acc0[d] = 0.f; acc1[d] = 0.f; }
    float mr0 = -1e30f, mr1 = -1e30f, l0 = 0.f, l1 = 0.f;

    const float* kb = k_ws + (size_t)bh * kN * kDH;
    const float* vb = v_ws + (size_t)bh * kN * kDH;
    const float* rp0 = rel + ((size_t)h * kN + r0) * kN;
    const float* rp1 = rp0 + kN;

    for (int c0 = 0; c0 < kN; c0 += 128) {
        int i = tid;
        #pragma unroll
        for (int rep = 0; rep < 4; rep++, i += 256) {   // 1024 float4 per matrix
            int rr = i >> 3, c4 = (i & 7) * 4;
            *reinterpret_cast<float4*>(&Ks[rr][c4]) =
                *reinterpret_cast<const float4*>(kb + (size_t)(c0 + rr) * kDH + c4);
            *reinterpret_cast<float4*>(&Vs[rr][c4]) =
                *reinterpret_cast<const float4*>(vb + (size_t)(c0 + rr) * kDH + c4);
        }
        __syncthreads();

        // scores for 8 m's per lane, 2 rows (q pre-scaled by 1/sqrt(dh))
        float s0[8], s1[8];
        #pragma unroll
        for (int ii = 0; ii < 8; ii++) {
            const int ml = sub + 16 * ii;
            float d0 = 0.f, d1 = 0.f;
            #pragma unroll
            for (int d4 = 0; d4 < 8; d4++) {
                float4 kv = *reinterpret_cast<const float4*>(&Ks[ml][d4 * 4]);
                d0 = fmaf(q0[d4 * 4 + 0], kv.x, d0); d1 = fmaf(q1[d4 * 4 + 0], kv.x, d1);
                d0 = fmaf(q0[d4 * 4 + 1], kv.y, d0); d1 = fmaf(q1[d4 * 4 + 1], kv.y, d1);
                d0 = fmaf(q0[d4 * 4 + 2], kv.z, d0); d1 = fmaf(q1[d4 * 4 + 2], kv.z, d1);
                d0 = fmaf(q0[d4 * 4 + 3], kv.w, d0); d1 = fmaf(q1[d4 * 4 + 3], kv.w, d1);
            }
            s0[ii] = d0 + rp0[c0 + ml];
            s1[ii] = d1 + rp1[c0 + ml];
        }

        // online softmax: chunk max -> reduce over 16 subs (xor 1,2,4,8)
        float cm0 = s0[0], cm1 = s1[0];
        #pragma unroll
        for (int ii = 1; ii < 8; ii++) { cm0 = fmaxf(cm0, s0[ii]); cm1 = fmaxf(cm1, s1[ii]); }
        #pragma unroll
        for (int off = 1; off < 16; off <<= 1) {
            cm0 = fmaxf(cm0, __shfl_xor(cm0, off));
            cm1 = fmaxf(cm1, __shfl_xor(cm1, off));
        }
        const float nm0 = fmaxf(mr0, cm0), nm1 = fmaxf(mr1, cm1);
        const float corr0 = __expf(mr0 - nm0), corr1 = __expf(mr1 - nm1);
        mr0 = nm0; mr1 = nm1;

        float ls0 = 0.f, ls1 = 0.f;
        #pragma unroll
        for (int ii = 0; ii < 8; ii++) {
            s0[ii] = __expf(s0[ii] - nm0); ls0 += s0[ii];
            s1[ii] = __expf(s1[ii] - nm1); ls1 += s1[ii];
        }
        #pragma unroll
        for (int off = 1; off < 16; off <<= 1) {
            ls0 += __shfl_xor(ls0, off);
            ls1 += __shfl_xor(ls1, off);
        }
        l0 = l0 * corr0 + ls0;
        l1 = l1 * corr1 + ls1;

        #pragma unroll
        for (int d = 0; d < 32; d++) { acc0[d] *= corr0; acc1[d] *= corr1; }
        #pragma unroll
        for (int ii = 0; ii < 8; ii++) {
            const int ml = sub + 16 * ii;
            const float p0 = s0[ii], p1 = s1[ii];
            #pragma unroll
            for (int d4 = 0; d4 < 8; d4++) {
                float4 vv = *reinterpret_cast<const float4*>(&Vs[ml][d4 * 4]);
                acc0[d4 * 4 + 0] = fmaf(p0, vv.x, acc0[d4 * 4 + 0]);
                acc0[d4 * 4 + 1] = fmaf(p0, vv.y, acc0[d4 * 4 + 1]);
                acc0[d4 * 4 + 2] = fmaf(p0, vv.z, acc0[d4 * 4 + 2]);
                acc0[d4 * 4 + 3] = fmaf(p0, vv.w, acc0[d4 * 4 + 3]);
                acc1[d4 * 4 + 0] = fmaf(p1, vv.x, acc1[d4 * 4 + 0]);
                acc1[d4 * 4 + 1] = fmaf(p1, vv.y, acc1[d4 * 4 + 1]);
                acc1[d4 * 4 + 2] = fmaf(p1, vv.z, acc1[d4 * 4 + 2]);
                acc1[d4 * 4 + 3] = fmaf(p1, vv.w, acc1[d4 * 4 + 3]);
            }
        }
        __syncthreads();   // protect LDS before next chunk's load
    }

    // cross-sub butterfly (static register indexing; rule-#20 safe)
    #pragma unroll
    for (int off = 1; off < 16; off <<= 1) {
        #pragma unroll
        for (int d = 0; d < 32; d++) {
            acc0[d] += __shfl_xor(acc0[d], off);
            acc1[d] += __shfl_xor(acc1[d], off);
        }
    }
    if (sub == 0) {   // every lane now holds the full rows; sub 0 writes them
        const float inv0 = 1.0f / l0, inv1 = 1.0f / l1;
        float* o0 = aout + ((size_t)bb * kN + r0) * kC + h * kDH;
        float* o1 = o0 + kC;
        #pragma unroll
        for (int d4 = 0; d4 < 8; d4++) {
            float4 w0, w1;
            w0.x = acc0[d4 * 4 + 0] * inv0; w0.y = acc0[d4 * 4 + 1] * inv0;
            w0.z = acc0[d4 * 4 + 2] * inv0; w0.w = acc0[d4 * 4 + 3] * inv0;
            w1.x = acc1[d4 * 4 + 0] * inv1; w1.y = acc1[d4 * 4 + 1] * inv1;
            w1.z = acc1[d4 * 4 + 2] * inv1; w1.w = acc1[d4 * 4 + 3] * inv1;
            *reinterpret_cast<float4*>(o0 + d4 * 4) = w0;
            *reinterpret_cast<float4*>(o1 + d4 * 4) = w1;
        }
    }
}

// ---------------- K3: output projection GEMM -------------------------------
__global__ __launch_bounds__(256) void proj_gemm(
    const float* __restrict__ A,      // attn out [8192,512]
    const float* __restrict__ W,      // [512,512]
    const float* __restrict__ bias,   // [512]
    float* __restrict__ out)          // [8192,512]
{
    __shared__ float As[32][64];
    __shared__ float Bs[32][64];
    const int tid = threadIdx.x;
    const int tx = tid & 15, ty = tid >> 4;
    const int m0 = blockIdx.x * 64, n0 = blockIdx.y * 64;

    float acc[4][4] = {};
    for (int k0 = 0; k0 < kC; k0 += 32) {
        int i = tid;
        #pragma unroll
        for (int rep = 0; rep < 2; rep++, i += 256) {
            int r = i >> 3, c4 = (i & 7) * 4;
            float4 v = *reinterpret_cast<const float4*>(A + (size_t)(m0 + r) * kC + k0 + c4);
            As[c4 + 0][r] = v.x;
            As[c4 + 1][r] = v.y;
            As[c4 + 2][r] = v.z;
            As[c4 + 3][r] = v.w;
        }
        i = tid;
        #pragma unroll
        for (int rep = 0; rep < 2; rep++, i += 256) {
            int r = i >> 4, c4 = (i & 15) * 4;
            *reinterpret_cast<float4*>(&Bs[r][c4]) =
                *reinterpret_cast<const float4*>(W + (size_t)(k0 + r) * kC + n0 + c4);
        }
        __syncthreads();
        #pragma unroll
        for (int k = 0; k < 32; k++) {
            float a[4], b[4];
            *reinterpret_cast<float4*>(a) = *reinterpret_cast<const float4*>(&As[k][ty * 4]);
            *reinterpret_cast<float4*>(b) = *reinterpret_cast<const float4*>(&Bs[k][tx * 4]);
            #pragma unroll
            for (int ii = 0; ii < 4; ii++)
                #pragma unroll
                for (int jj = 0; jj < 4; jj++)
                    acc[ii][jj] = fmaf(a[ii], b[jj], acc[ii][jj]);
        }
        __syncthreads();
    }

    const float4 bv = *reinterpret_cast<const float4*>(bias + n0 + tx * 4);
    #pragma unroll
    for (int ii = 0; ii < 4; ii++) {
        float4 v;
        v.x = acc[ii][0] + bv.x;
        v.y = acc[ii][1] + bv.y;
        v.z = acc[ii][2] + bv.z;
        v.w = acc[ii][3] + bv.w;
        *reinterpret_cast<float4*>(out + (size_t)(m0 + ty * 4 + ii) * kC + n0 + tx * 4) = v;
    }
}

// ---------------------------------------------------------------------------
extern "C" void kernel_launch(void* const* d_in, const int* in_sizes, int n_in,
                              void* d_out, int out_size, void* d_ws, size_t ws_size,
                              hipStream_t stream) {
    const float* x     = (const float*)d_in[0];
    const float* rel   = (const float*)d_in[1];
    const float* Wqkv  = (const float*)d_in[2];
    const float* bqkv  = (const float*)d_in[3];
    const float* Wproj = (const float*)d_in[4];
    const float* bproj = (const float*)d_in[5];
    float* out = (float*)d_out;

    float* ws = (float*)d_ws;
    const size_t qkv_elems = (size_t)kB * kNH * kN * kDH;   // 4M floats each
    float* q_ws = ws;
    float* k_ws = q_ws + qkv_elems;
    float* v_ws = k_ws + qkv_elems;
    float* a_ws = v_ws + qkv_elems;                          // [8192,512]

    qkv_gemm<<<dim3(kBN / 64, kQKV / 64), 256, 0, stream>>>(x, Wqkv, bqkv, q_ws, k_ws, v_ws);
    attn_kernel<<<dim3(kN / 32, kB * kNH), 256, 0, stream>>>(q_ws, k_ws, v_ws, rel, a_ws);
    proj_gemm<<<dim3(kBN / 64, kC / 64), 256, 0, stream>>>(a_ws, Wproj, bproj, out);
}

// Round 2
// 451.981 us; speedup vs baseline: 1.8086x; 1.8086x over previous
//
#include <hip/hip_runtime.h>
#include <math.h>

// ---------------------------------------------------------------------------
// AttentionCl fused block, round 2: bf16-MFMA attention.
//   K1: qkv_gemm  (fp32 compute) -> scatter Q(scaled),K,V as bf16 [B,H,N,32]
//   K2: attn      : MFMA 16x16x32 bf16 QK^T + PV, fp32 online softmax,
//                   rel bias added in fp32. out a_ws fp32 [8192,512]
//   K3: proj_gemm : fp32 (unchanged)
// ---------------------------------------------------------------------------

constexpr int kB  = 8;
constexpr int kNH = 16;
constexpr int kDH = 32;
constexpr int kC  = 512;
constexpr int kN  = 1024;
constexpr int kBN = kB * kN;        // 8192
constexpr int kQKV = 3 * kNH * kDH; // 1536

typedef __attribute__((ext_vector_type(8))) short bf16x8;   // 8 bf16 = 4 VGPRs
typedef __attribute__((ext_vector_type(4))) float f32x4;

__device__ __forceinline__ unsigned short f2bf(float f) {
    unsigned int u = __float_as_uint(f);
    unsigned int r = (u + 0x7FFFu + ((u >> 16) & 1u)) >> 16;   // RNE
    return (unsigned short)r;
}

// ---------------- K1: QKV projection GEMM + bf16 scatter --------------------
__global__ __launch_bounds__(256) void qkv_gemm(
    const float* __restrict__ A,      // x [8192,512]
    const float* __restrict__ Bw,     // W_qkv [512,1536]
    const float* __restrict__ bias,   // [1536]
    unsigned short* __restrict__ q_ws,
    unsigned short* __restrict__ k_ws,
    unsigned short* __restrict__ v_ws)
{
    __shared__ float As[32][64];      // A^T tile
    __shared__ float Bs[32][64];
    const int tid = threadIdx.x;
    const int tx = tid & 15, ty = tid >> 4;
    const int m0 = blockIdx.x * 64;
    const int n0 = blockIdx.y * 64;

    float acc[4][4] = {};
    for (int k0 = 0; k0 < kC; k0 += 32) {
        int i = tid;
        #pragma unroll
        for (int rep = 0; rep < 2; rep++, i += 256) {
            int r = i >> 3, c4 = (i & 7) * 4;
            float4 v = *reinterpret_cast<const float4*>(A + (size_t)(m0 + r) * kC + k0 + c4);
            As[c4 + 0][r] = v.x;
            As[c4 + 1][r] = v.y;
            As[c4 + 2][r] = v.z;
            As[c4 + 3][r] = v.w;
        }
        i = tid;
        #pragma unroll
        for (int rep = 0; rep < 2; rep++, i += 256) {
            int r = i >> 4, c4 = (i & 15) * 4;
            *reinterpret_cast<float4*>(&Bs[r][c4]) =
                *reinterpret_cast<const float4*>(Bw + (size_t)(k0 + r) * kQKV + n0 + c4);
        }
        __syncthreads();
        #pragma unroll
        for (int k = 0; k < 32; k++) {
            float a[4], b[4];
            *reinterpret_cast<float4*>(a) = *reinterpret_cast<const float4*>(&As[k][ty * 4]);
            *reinterpret_cast<float4*>(b) = *reinterpret_cast<const float4*>(&Bs[k][tx * 4]);
            #pragma unroll
            for (int ii = 0; ii < 4; ii++)
                #pragma unroll
                for (int jj = 0; jj < 4; jj++)
                    acc[ii][jj] = fmaf(a[ii], b[jj], acc[ii][jj]);
        }
        __syncthreads();
    }

    const float scale = 0.17677669529663687f;   // 1/sqrt(32) folded into Q
    const int col0 = n0 + tx * 4;
    const int head = col0 / 96;
    const int r = col0 - head * 96;
    const float4 bv = *reinterpret_cast<const float4*>(bias + col0);
    #pragma unroll
    for (int ii = 0; ii < 4; ii++) {
        const int m = m0 + ty * 4 + ii;
        const int bb = m >> 10, n = m & 1023;
        float4 v;
        v.x = acc[ii][0] + bv.x;
        v.y = acc[ii][1] + bv.y;
        v.z = acc[ii][2] + bv.z;
        v.w = acc[ii][3] + bv.w;
        const size_t base = ((size_t)(bb * kNH + head) * kN + n) * kDH;
        ushort4 pk;
        if (r < 32) {
            pk.x = f2bf(v.x * scale); pk.y = f2bf(v.y * scale);
            pk.z = f2bf(v.z * scale); pk.w = f2bf(v.w * scale);
            *reinterpret_cast<ushort4*>(q_ws + base + r) = pk;
        } else if (r < 64) {
            pk.x = f2bf(v.x); pk.y = f2bf(v.y); pk.z = f2bf(v.z); pk.w = f2bf(v.w);
            *reinterpret_cast<ushort4*>(k_ws + base + (r - 32)) = pk;
        } else {
            pk.x = f2bf(v.x); pk.y = f2bf(v.y); pk.z = f2bf(v.z); pk.w = f2bf(v.w);
            *reinterpret_cast<ushort4*>(v_ws + base + (r - 64)) = pk;
        }
    }
}

// ---------------- K2: MFMA flash attention ---------------------------------
// grid (N/64, B*NH) with y -> h = y>>3, b = y&7 (same-(h,qtile) blocks share
// XCD for rel-bias L2 reuse). 4 waves, wave w owns q-rows [x*64+w*16, +16).
// m-chunks of 64: K staged [64][72] bf16 (2-way-free b128 reads), V staged
// transposed Vt[32][72], P per-wave [16][72].
__global__ __launch_bounds__(256) void attn_kernel(
    const unsigned short* __restrict__ q_ws,
    const unsigned short* __restrict__ k_ws,
    const unsigned short* __restrict__ v_ws,
    const float* __restrict__ rel,
    float* __restrict__ aout)    // [8192, 512] fp32
{
    __shared__ unsigned short Ks[64 * 72];
    __shared__ unsigned short Vt[32 * 72];
    __shared__ unsigned short Pl[4][16 * 72];

    const int tid  = threadIdx.x;
    const int wave = tid >> 6;
    const int lane = tid & 63;
    const int col  = lane & 15;      // MFMA col / A-row index
    const int hi   = lane >> 4;      // 0..3
    const int h = blockIdx.y >> 3;
    const int b = blockIdx.y & 7;
    const int bh = b * kNH + h;
    const int r0 = blockIdx.x * 64 + wave * 16;

    // Q A-fragment: lane holds Q[r0+col][8*hi + j], j=0..7 (16B, resident)
    const bf16x8 q_frag = *reinterpret_cast<const bf16x8*>(
        q_ws + ((size_t)bh * kN + r0 + col) * kDH + 8 * hi);

    const unsigned short* kb = k_ws + (size_t)bh * kN * kDH;
    const unsigned short* vb = v_ws + (size_t)bh * kN * kDH;
    // bias base for this lane's column; row term added per (hi,reg)
    const float* relb = rel + ((size_t)h * kN + r0) * kN + col;

    f32x4 o0 = {0.f, 0.f, 0.f, 0.f};
    f32x4 o1 = {0.f, 0.f, 0.f, 0.f};
    float mrun[4] = {-1e30f, -1e30f, -1e30f, -1e30f};
    float lrun[4] = {0.f, 0.f, 0.f, 0.f};

    const int srow = tid >> 2;            // staging: row 0..63
    const int sd0  = (tid & 3) * 8;       // staging: d offset 0/8/16/24

    for (int c0 = 0; c0 < kN; c0 += 64) {
        // ---- stage K and V^T ----
        {
            bf16x8 kv = *reinterpret_cast<const bf16x8*>(kb + (size_t)(c0 + srow) * kDH + sd0);
            *reinterpret_cast<bf16x8*>(&Ks[srow * 72 + sd0]) = kv;
            bf16x8 vv = *reinterpret_cast<const bf16x8*>(vb + (size_t)(c0 + srow) * kDH + sd0);
            #pragma unroll
            for (int j = 0; j < 8; j++)
                Vt[(sd0 + j) * 72 + srow] = (unsigned short)vv[j];
        }
        __syncthreads();

        // ---- QK^T: 4 m-tiles of 16 ----
        f32x4 s[4];
        #pragma unroll
        for (int t = 0; t < 4; t++) {
            const bf16x8 kf = *reinterpret_cast<const bf16x8*>(&Ks[(t * 16 + col) * 72 + 8 * hi]);
            const f32x4 z = {0.f, 0.f, 0.f, 0.f};
            s[t] = __builtin_amdgcn_mfma_f32_16x16x32_bf16(q_frag, kf, z, 0, 0, 0);
        }

        // ---- + rel bias (fp32, global) ----
        #pragma unroll
        for (int t = 0; t < 4; t++)
            #pragma unroll
            for (int reg = 0; reg < 4; reg++)
                s[t][reg] += relb[(size_t)(4 * hi + reg) * kN + c0 + t * 16];

        // ---- online softmax (rows = 4*hi+reg; cols across 16 lanes) ----
        float cm[4], nm[4], corr[4], psum[4];
        #pragma unroll
        for (int reg = 0; reg < 4; reg++) {
            cm[reg] = fmaxf(fmaxf(s[0][reg], s[1][reg]), fmaxf(s[2][reg], s[3][reg]));
            #pragma unroll
            for (int off = 1; off < 16; off <<= 1)
                cm[reg] = fmaxf(cm[reg], __shfl_xor(cm[reg], off));
            nm[reg] = fmaxf(mrun[reg], cm[reg]);
            corr[reg] = __expf(mrun[reg] - nm[reg]);
            mrun[reg] = nm[reg];
            psum[reg] = 0.f;
        }
        #pragma unroll
        for (int t = 0; t < 4; t++)
            #pragma unroll
            for (int reg = 0; reg < 4; reg++) {
                s[t][reg] = __expf(s[t][reg] - nm[reg]);
                psum[reg] += s[t][reg];
            }
        #pragma unroll
        for (int reg = 0; reg < 4; reg++) {
            #pragma unroll
            for (int off = 1; off < 16; off <<= 1)
                psum[reg] += __shfl_xor(psum[reg], off);
            lrun[reg] = lrun[reg] * corr[reg] + psum[reg];
            o0[reg] *= corr[reg];
            o1[reg] *= corr[reg];
        }

        // ---- P -> bf16 -> per-wave LDS (C-layout scatter) ----
        unsigned short* pw = &Pl[wave][0];
        #pragma unroll
        for (int t = 0; t < 4; t++)
            #pragma unroll
            for (int reg = 0; reg < 4; reg++)
                pw[(4 * hi + reg) * 72 + t * 16 + col] = f2bf(s[t][reg]);
        // same-wave LDS write->read: lgkmcnt ordering, no barrier needed

        // ---- PV: O += P[16x32half] * V[32half x 32d] ----
        #pragma unroll
        for (int half = 0; half < 2; half++) {
            const bf16x8 pa = *reinterpret_cast<const bf16x8*>(
                &Pl[wave][col * 72 + half * 32 + 8 * hi]);
            const bf16x8 v0 = *reinterpret_cast<const bf16x8*>(
                &Vt[(0 * 16 + col) * 72 + half * 32 + 8 * hi]);
            const bf16x8 v1 = *reinterpret_cast<const bf16x8*>(
                &Vt[(1 * 16 + col) * 72 + half * 32 + 8 * hi]);
            o0 = __builtin_amdgcn_mfma_f32_16x16x32_bf16(pa, v0, o0, 0, 0, 0);
            o1 = __builtin_amdgcn_mfma_f32_16x16x32_bf16(pa, v1, o1, 0, 0, 0);
        }
        __syncthreads();   // protect Ks/Vt before next chunk's stage
    }

    // ---- epilogue ----
    #pragma unroll
    for (int reg = 0; reg < 4; reg++) {
        const float inv = 1.0f / lrun[reg];
        float* orow = aout + ((size_t)b * kN + r0 + 4 * hi + reg) * kC + h * kDH;
        orow[col]      = o0[reg] * inv;
        orow[16 + col] = o1[reg] * inv;
    }
}

// ---------------- K3: output projection GEMM (fp32, unchanged) -------------
__global__ __launch_bounds__(256) void proj_gemm(
    const float* __restrict__ A,      // attn out [8192,512]
    const float* __restrict__ W,      // [512,512]
    const float* __restrict__ bias,   // [512]
    float* __restrict__ out)
{
    __shared__ float As[32][64];
    __shared__ float Bs[32][64];
    const int tid = threadIdx.x;
    const int tx = tid & 15, ty = tid >> 4;
    const int m0 = blockIdx.x * 64, n0 = blockIdx.y * 64;

    float acc[4][4] = {};
    for (int k0 = 0; k0 < kC; k0 += 32) {
        int i = tid;
        #pragma unroll
        for (int rep = 0; rep < 2; rep++, i += 256) {
            int r = i >> 3, c4 = (i & 7) * 4;
            float4 v = *reinterpret_cast<const float4*>(A + (size_t)(m0 + r) * kC + k0 + c4);
            As[c4 + 0][r] = v.x;
            As[c4 + 1][r] = v.y;
            As[c4 + 2][r] = v.z;
            As[c4 + 3][r] = v.w;
        }
        i = tid;
        #pragma unroll
        for (int rep = 0; rep < 2; rep++, i += 256) {
            int r = i >> 4, c4 = (i & 15) * 4;
            *reinterpret_cast<float4*>(&Bs[r][c4]) =
                *reinterpret_cast<const float4*>(W + (size_t)(k0 + r) * kC + n0 + c4);
        }
        __syncthreads();
        #pragma unroll
        for (int k = 0; k < 32; k++) {
            float a[4], bq[4];
            *reinterpret_cast<float4*>(a)  = *reinterpret_cast<const float4*>(&As[k][ty * 4]);
            *reinterpret_cast<float4*>(bq) = *reinterpret_cast<const float4*>(&Bs[k][tx * 4]);
            #pragma unroll
            for (int ii = 0; ii < 4; ii++)
                #pragma unroll
                for (int jj = 0; jj < 4; jj++)
                    acc[ii][jj] = fmaf(a[ii], bq[jj], acc[ii][jj]);
        }
        __syncthreads();
    }

    const float4 bv = *reinterpret_cast<const float4*>(bias + n0 + tx * 4);
    #pragma unroll
    for (int ii = 0; ii < 4; ii++) {
        float4 v;
        v.x = acc[ii][0] + bv.x;
        v.y = acc[ii][1] + bv.y;
        v.z = acc[ii][2] + bv.z;
        v.w = acc[ii][3] + bv.w;
        *reinterpret_cast<float4*>(out + (size_t)(m0 + ty * 4 + ii) * kC + n0 + tx * 4) = v;
    }
}

// ---------------------------------------------------------------------------
extern "C" void kernel_launch(void* const* d_in, const int* in_sizes, int n_in,
                              void* d_out, int out_size, void* d_ws, size_t ws_size,
                              hipStream_t stream) {
    const float* x     = (const float*)d_in[0];
    const float* rel   = (const float*)d_in[1];
    const float* Wqkv  = (const float*)d_in[2];
    const float* bqkv  = (const float*)d_in[3];
    const float* Wproj = (const float*)d_in[4];
    const float* bproj = (const float*)d_in[5];
    float* out = (float*)d_out;

    const size_t qkv_elems = (size_t)kB * kNH * kN * kDH;   // 4M elements
    unsigned short* q_ws = (unsigned short*)d_ws;
    unsigned short* k_ws = q_ws + qkv_elems;
    unsigned short* v_ws = k_ws + qkv_elems;
    float* a_ws = (float*)(v_ws + qkv_elems);               // [8192,512] fp32

    qkv_gemm<<<dim3(kBN / 64, kQKV / 64), 256, 0, stream>>>(x, Wqkv, bqkv, q_ws, k_ws, v_ws);
    attn_kernel<<<dim3(kN / 64, kB * kNH), 256, 0, stream>>>(q_ws, k_ws, v_ws, rel, a_ws);
    proj_gemm<<<dim3(kBN / 64, kC / 64), 256, 0, stream>>>(a_ws, Wproj, bproj, out);
}

// Round 3
// 262.667 us; speedup vs baseline: 3.1121x; 1.7207x over previous
//
#include <hip/hip_runtime.h>
#include <math.h>

// ---------------------------------------------------------------------------
// AttentionCl fused block, round 3: all-bf16-MFMA pipeline.
//   K0a convert_x        : x fp32 -> xb bf16 [8192][512]
//   K0b transpose_convert: W_qkv -> Wqt bf16 [1536][512]; W_proj -> Wpt [512][512]
//   K1  qkv_mfma         : xb @ Wqt^T + b -> scatter Q(scaled)/K/V bf16 [B,H,N,32]
//   K2  attn             : MFMA flash attention (unchanged) -> a_ws bf16 [8192][512]
//   K3  proj_mfma        : a_ws @ Wpt^T + b -> d_out fp32
// ---------------------------------------------------------------------------

constexpr int kB  = 8;
constexpr int kNH = 16;
constexpr int kDH = 32;
constexpr int kC  = 512;
constexpr int kN  = 1024;
constexpr int kBN = kB * kN;        // 8192
constexpr int kQKV = 3 * kNH * kDH; // 1536

typedef __attribute__((ext_vector_type(8))) short bf16x8;
typedef __attribute__((ext_vector_type(4))) float f32x4;

__device__ __forceinline__ unsigned short f2bf(float f) {
    unsigned int u = __float_as_uint(f);
    unsigned int r = (u + 0x7FFFu + ((u >> 16) & 1u)) >> 16;   // RNE
    return (unsigned short)r;
}

// ---------------- K0a: elementwise fp32 -> bf16 ----------------------------
__global__ __launch_bounds__(256) void convert_x(
    const float* __restrict__ in, unsigned short* __restrict__ out)
{
    const int i = blockIdx.x * 256 + threadIdx.x;   // one float4 per thread
    float4 v = reinterpret_cast<const float4*>(in)[i];
    ushort4 o;
    o.x = f2bf(v.x); o.y = f2bf(v.y); o.z = f2bf(v.z); o.w = f2bf(v.w);
    reinterpret_cast<ushort4*>(out)[i] = o;
}

// ---------------- K0b: transpose + convert: in[R][C] fp32 -> out[C][R] bf16 -
__global__ __launch_bounds__(256) void transpose_convert(
    const float* __restrict__ in, unsigned short* __restrict__ out, int R, int C)
{
    __shared__ float T[64][65];
    const int tid = threadIdx.x;
    const int c0 = blockIdx.x * 64, r0 = blockIdx.y * 64;
    #pragma unroll
    for (int p = 0; p < 4; p++) {                       // load 64x64 fp32 tile
        const int r = (tid >> 4) + p * 16, c = (tid & 15) * 4;
        float4 v = *reinterpret_cast<const float4*>(in + (size_t)(r0 + r) * C + c0 + c);
        T[r][c + 0] = v.x; T[r][c + 1] = v.y; T[r][c + 2] = v.z; T[r][c + 3] = v.w;
    }
    __syncthreads();
    #pragma unroll
    for (int p = 0; p < 4; p++) {                       // write transposed bf16
        const int c = (tid >> 4) + p * 16, r4 = (tid & 15) * 4;
        ushort4 w;
        w.x = f2bf(T[r4 + 0][c]); w.y = f2bf(T[r4 + 1][c]);
        w.z = f2bf(T[r4 + 2][c]); w.w = f2bf(T[r4 + 3][c]);
        *reinterpret_cast<ushort4*>(out + (size_t)(c0 + c) * R + r0 + r4) = w;
    }
}

// ---------------- K1: QKV MFMA GEMM + bf16 scatter --------------------------
// C[8192][1536] = xb @ Wqt^T. 128x128 tile, BK=64, 4 waves (2x2), each wave
// 64x64 = 4x4 MFMA frags. LDS stride 72 shorts (144B) -> 2-way-free b128.
__global__ __launch_bounds__(256) void qkv_mfma(
    const unsigned short* __restrict__ A,    // xb [8192][512]
    const unsigned short* __restrict__ Bt,   // Wqt [1536][512]
    const float* __restrict__ bias,          // [1536]
    unsigned short* __restrict__ q_ws,
    unsigned short* __restrict__ k_ws,
    unsigned short* __restrict__ v_ws)
{
    __shared__ unsigned short As[128 * 72];
    __shared__ unsigned short Bs[128 * 72];
    const int tid = threadIdx.x;
    const int wave = tid >> 6, lane = tid & 63;
    const int col = lane & 15, hi = lane >> 4;
    const int wr = wave >> 1, wc = wave & 1;
    const int m0 = blockIdx.x * 128, n0 = blockIdx.y * 128;

    f32x4 acc[4][4] = {};
    for (int k0 = 0; k0 < kC; k0 += 64) {
        #pragma unroll
        for (int i = 0; i < 4; i++) {
            const int ch = i * 256 + tid, row = ch >> 3, cc = (ch & 7) * 8;
            *reinterpret_cast<bf16x8*>(&As[row * 72 + cc]) =
                *reinterpret_cast<const bf16x8*>(A + (size_t)(m0 + row) * kC + k0 + cc);
            *reinterpret_cast<bf16x8*>(&Bs[row * 72 + cc]) =
                *reinterpret_cast<const bf16x8*>(Bt + (size_t)(n0 + row) * kC + k0 + cc);
        }
        __syncthreads();
        #pragma unroll
        for (int kk = 0; kk < 2; kk++) {
            bf16x8 af[4], bfr[4];
            #pragma unroll
            for (int mt = 0; mt < 4; mt++)
                af[mt] = *reinterpret_cast<const bf16x8*>(
                    &As[(wr * 64 + mt * 16 + col) * 72 + kk * 32 + 8 * hi]);
            #pragma unroll
            for (int nt = 0; nt < 4; nt++)
                bfr[nt] = *reinterpret_cast<const bf16x8*>(
                    &Bs[(wc * 64 + nt * 16 + col) * 72 + kk * 32 + 8 * hi]);
            #pragma unroll
            for (int mt = 0; mt < 4; mt++)
                #pragma unroll
                for (int nt = 0; nt < 4; nt++)
                    acc[mt][nt] = __builtin_amdgcn_mfma_f32_16x16x32_bf16(
                        af[mt], bfr[nt], acc[mt][nt], 0, 0, 0);
        }
        __syncthreads();
    }

    // epilogue: bias + scale-Q + bf16 scatter. C[m][n]: m = m0+wr*64+mt*16+4*hi+reg,
    // n = n0+wc*64+nt*16+col. head = n/96, r = n%96; 16-col groups never straddle.
    const float scale = 0.17677669529663687f;
    #pragma unroll
    for (int nt = 0; nt < 4; nt++) {
        const int n = n0 + wc * 64 + nt * 16 + col;
        const int head = n / 96;
        const int r = n - head * 96;
        const float bv = bias[n];
        #pragma unroll
        for (int mt = 0; mt < 4; mt++)
            #pragma unroll
            for (int reg = 0; reg < 4; reg++) {
                const int m = m0 + wr * 64 + mt * 16 + 4 * hi + reg;
                const int bb = m >> 10, np = m & 1023;
                const float v = acc[mt][nt][reg] + bv;
                const size_t base = ((size_t)(bb * kNH + head) * kN + np) * kDH;
                if (r < 32)      q_ws[base + r]      = f2bf(v * scale);
                else if (r < 64) k_ws[base + r - 32] = f2bf(v);
                else             v_ws[base + r - 64] = f2bf(v);
            }
    }
}

// ---------------- K2: MFMA flash attention (out now bf16) -------------------
__global__ __launch_bounds__(256) void attn_kernel(
    const unsigned short* __restrict__ q_ws,
    const unsigned short* __restrict__ k_ws,
    const unsigned short* __restrict__ v_ws,
    const float* __restrict__ rel,
    unsigned short* __restrict__ aout)    // [8192, 512] bf16
{
    __shared__ unsigned short Ks[64 * 72];
    __shared__ unsigned short Vt[32 * 72];
    __shared__ unsigned short Pl[4][16 * 72];

    const int tid  = threadIdx.x;
    const int wave = tid >> 6;
    const int lane = tid & 63;
    const int col  = lane & 15;
    const int hi   = lane >> 4;
    const int h = blockIdx.y >> 3;
    const int b = blockIdx.y & 7;
    const int bh = b * kNH + h;
    const int r0 = blockIdx.x * 64 + wave * 16;

    const bf16x8 q_frag = *reinterpret_cast<const bf16x8*>(
        q_ws + ((size_t)bh * kN + r0 + col) * kDH + 8 * hi);

    const unsigned short* kb = k_ws + (size_t)bh * kN * kDH;
    const unsigned short* vb = v_ws + (size_t)bh * kN * kDH;
    const float* relb = rel + ((size_t)h * kN + r0) * kN + col;

    f32x4 o0 = {0.f, 0.f, 0.f, 0.f};
    f32x4 o1 = {0.f, 0.f, 0.f, 0.f};
    float mrun[4] = {-1e30f, -1e30f, -1e30f, -1e30f};
    float lrun[4] = {0.f, 0.f, 0.f, 0.f};

    const int srow = tid >> 2;
    const int sd0  = (tid & 3) * 8;

    for (int c0 = 0; c0 < kN; c0 += 64) {
        {
            bf16x8 kv = *reinterpret_cast<const bf16x8*>(kb + (size_t)(c0 + srow) * kDH + sd0);
            *reinterpret_cast<bf16x8*>(&Ks[srow * 72 + sd0]) = kv;
            bf16x8 vv = *reinterpret_cast<const bf16x8*>(vb + (size_t)(c0 + srow) * kDH + sd0);
            #pragma unroll
            for (int j = 0; j < 8; j++)
                Vt[(sd0 + j) * 72 + srow] = (unsigned short)vv[j];
        }
        __syncthreads();

        f32x4 s[4];
        #pragma unroll
        for (int t = 0; t < 4; t++) {
            const bf16x8 kf = *reinterpret_cast<const bf16x8*>(&Ks[(t * 16 + col) * 72 + 8 * hi]);
            const f32x4 z = {0.f, 0.f, 0.f, 0.f};
            s[t] = __builtin_amdgcn_mfma_f32_16x16x32_bf16(q_frag, kf, z, 0, 0, 0);
        }

        #pragma unroll
        for (int t = 0; t < 4; t++)
            #pragma unroll
            for (int reg = 0; reg < 4; reg++)
                s[t][reg] += relb[(size_t)(4 * hi + reg) * kN + c0 + t * 16];

        float cm[4], nm[4], corr[4], psum[4];
        #pragma unroll
        for (int reg = 0; reg < 4; reg++) {
            cm[reg] = fmaxf(fmaxf(s[0][reg], s[1][reg]), fmaxf(s[2][reg], s[3][reg]));
            #pragma unroll
            for (int off = 1; off < 16; off <<= 1)
                cm[reg] = fmaxf(cm[reg], __shfl_xor(cm[reg], off));
            nm[reg] = fmaxf(mrun[reg], cm[reg]);
            corr[reg] = __expf(mrun[reg] - nm[reg]);
            mrun[reg] = nm[reg];
            psum[reg] = 0.f;
        }
        #pragma unroll
        for (int t = 0; t < 4; t++)
            #pragma unroll
            for (int reg = 0; reg < 4; reg++) {
                s[t][reg] = __expf(s[t][reg] - nm[reg]);
                psum[reg] += s[t][reg];
            }
        #pragma unroll
        for (int reg = 0; reg < 4; reg++) {
            #pragma unroll
            for (int off = 1; off < 16; off <<= 1)
                psum[reg] += __shfl_xor(psum[reg], off);
            lrun[reg] = lrun[reg] * corr[reg] + psum[reg];
            o0[reg] *= corr[reg];
            o1[reg] *= corr[reg];
        }

        unsigned short* pw = &Pl[wave][0];
        #pragma unroll
        for (int t = 0; t < 4; t++)
            #pragma unroll
            for (int reg = 0; reg < 4; reg++)
                pw[(4 * hi + reg) * 72 + t * 16 + col] = f2bf(s[t][reg]);

        #pragma unroll
        for (int half = 0; half < 2; half++) {
            const bf16x8 pa = *reinterpret_cast<const bf16x8*>(
                &Pl[wave][col * 72 + half * 32 + 8 * hi]);
            const bf16x8 v0 = *reinterpret_cast<const bf16x8*>(
                &Vt[(0 * 16 + col) * 72 + half * 32 + 8 * hi]);
            const bf16x8 v1 = *reinterpret_cast<const bf16x8*>(
                &Vt[(1 * 16 + col) * 72 + half * 32 + 8 * hi]);
            o0 = __builtin_amdgcn_mfma_f32_16x16x32_bf16(pa, v0, o0, 0, 0, 0);
            o1 = __builtin_amdgcn_mfma_f32_16x16x32_bf16(pa, v1, o1, 0, 0, 0);
        }
        __syncthreads();
    }

    #pragma unroll
    for (int reg = 0; reg < 4; reg++) {
        const float inv = 1.0f / lrun[reg];
        unsigned short* orow = aout + ((size_t)b * kN + r0 + 4 * hi + reg) * kC + h * kDH;
        orow[col]      = f2bf(o0[reg] * inv);
        orow[16 + col] = f2bf(o1[reg] * inv);
    }
}

// ---------------- K3: output projection MFMA GEMM ---------------------------
__global__ __launch_bounds__(256) void proj_mfma(
    const unsigned short* __restrict__ A,    // a_ws bf16 [8192][512]
    const unsigned short* __restrict__ Bt,   // Wpt bf16 [512][512]
    const float* __restrict__ bias,          // [512]
    float* __restrict__ out)                 // [8192][512] fp32
{
    __shared__ unsigned short As[128 * 72];
    __shared__ unsigned short Bs[128 * 72];
    const int tid = threadIdx.x;
    const int wave = tid >> 6, lane = tid & 63;
    const int col = lane & 15, hi = lane >> 4;
    const int wr = wave >> 1, wc = wave & 1;
    const int m0 = blockIdx.x * 128, n0 = blockIdx.y * 128;

    f32x4 acc[4][4] = {};
    for (int k0 = 0; k0 < kC; k0 += 64) {
        #pragma unroll
        for (int i = 0; i < 4; i++) {
            const int ch = i * 256 + tid, row = ch >> 3, cc = (ch & 7) * 8;
            *reinterpret_cast<bf16x8*>(&As[row * 72 + cc]) =
                *reinterpret_cast<const bf16x8*>(A + (size_t)(m0 + row) * kC + k0 + cc);
            *reinterpret_cast<bf16x8*>(&Bs[row * 72 + cc]) =
                *reinterpret_cast<const bf16x8*>(Bt + (size_t)(n0 + row) * kC + k0 + cc);
        }
        __syncthreads();
        #pragma unroll
        for (int kk = 0; kk < 2; kk++) {
            bf16x8 af[4], bfr[4];
            #pragma unroll
            for (int mt = 0; mt < 4; mt++)
                af[mt] = *reinterpret_cast<const bf16x8*>(
                    &As[(wr * 64 + mt * 16 + col) * 72 + kk * 32 + 8 * hi]);
            #pragma unroll
            for (int nt = 0; nt < 4; nt++)
                bfr[nt] = *reinterpret_cast<const bf16x8*>(
                    &Bs[(wc * 64 + nt * 16 + col) * 72 + kk * 32 + 8 * hi]);
            #pragma unroll
            for (int mt = 0; mt < 4; mt++)
                #pragma unroll
                for (int nt = 0; nt < 4; nt++)
                    acc[mt][nt] = __builtin_amdgcn_mfma_f32_16x16x32_bf16(
                        af[mt], bfr[nt], acc[mt][nt], 0, 0, 0);
        }
        __syncthreads();
    }

    #pragma unroll
    for (int nt = 0; nt < 4; nt++) {
        const int n = n0 + wc * 64 + nt * 16 + col;
        const float bv = bias[n];
        #pragma unroll
        for (int mt = 0; mt < 4; mt++)
            #pragma unroll
            for (int reg = 0; reg < 4; reg++) {
                const int m = m0 + wr * 64 + mt * 16 + 4 * hi + reg;
                out[(size_t)m * kC + n] = acc[mt][nt][reg] + bv;
            }
    }
}

// ---------------------------------------------------------------------------
extern "C" void kernel_launch(void* const* d_in, const int* in_sizes, int n_in,
                              void* d_out, int out_size, void* d_ws, size_t ws_size,
                              hipStream_t stream) {
    const float* x     = (const float*)d_in[0];
    const float* rel   = (const float*)d_in[1];
    const float* Wqkv  = (const float*)d_in[2];
    const float* bqkv  = (const float*)d_in[3];
    const float* Wproj = (const float*)d_in[4];
    const float* bproj = (const float*)d_in[5];
    float* out = (float*)d_out;

    unsigned short* ws = (unsigned short*)d_ws;
    const size_t qkv_elems = (size_t)kB * kNH * kN * kDH;   // 4M
    unsigned short* q_ws = ws;                    ws += qkv_elems;
    unsigned short* k_ws = ws;                    ws += qkv_elems;
    unsigned short* v_ws = ws;                    ws += qkv_elems;
    unsigned short* a_ws = ws;                    ws += (size_t)kBN * kC;
    unsigned short* xb   = ws;                    ws += (size_t)kBN * kC;
    unsigned short* Wqt  = ws;                    ws += (size_t)kQKV * kC;
    unsigned short* Wpt  = ws;                    ws += (size_t)kC * kC;

    convert_x<<<dim3(kBN * kC / 4 / 256), 256, 0, stream>>>(x, xb);
    transpose_convert<<<dim3(kQKV / 64, kC / 64), 256, 0, stream>>>(Wqkv, Wqt, kC, kQKV);
    transpose_convert<<<dim3(kC / 64, kC / 64), 256, 0, stream>>>(Wproj, Wpt, kC, kC);

    qkv_mfma<<<dim3(kBN / 128, kQKV / 128), 256, 0, stream>>>(xb, Wqt, bqkv, q_ws, k_ws, v_ws);
    attn_kernel<<<dim3(kN / 64, kB * kNH), 256, 0, stream>>>(q_ws, k_ws, v_ws, rel, a_ws);
    proj_mfma<<<dim3(kBN / 128, kC / 128), 256, 0, stream>>>(a_ws, Wpt, bproj, out);
}

// Round 6
// 237.512 us; speedup vs baseline: 3.4418x; 1.1059x over previous
//
#include <hip/hip_runtime.h>
#include <math.h>

// ---------------------------------------------------------------------------
// AttentionCl fused block, round 6: swapped-QK^T attention, PV via verified
// 16x16x32 path (R4's 16x16x16/cvt_pk PV — the unverified primitives — removed
// after the 2.18e-2 correctness failure).
//   K1  qkv_mfma : xb @ Wqt^T + b -> Q(*1/sqrt(dh)*log2e) bf16 [bh][n][32],
//                  K bf16 [bh][n][32], V TRANSPOSED bf16 [bh][32][n]
//   K2  attn     : S = mfma(K,Q) -> lane holds S[k][q=col]; softmax in-lane
//                  (exp2 domain); P -> per-wave LDS [q][key] via f2bf;
//                  PV = R3-verified 16x16x32 block -> O[q=4hi+reg][d=col].
//   K3  proj_mfma: a_ws bf16 @ Wpt^T + b -> out fp32
// ---------------------------------------------------------------------------

constexpr int kB  = 8;
constexpr int kNH = 16;
constexpr int kDH = 32;
constexpr int kC  = 512;
constexpr int kN  = 1024;
constexpr int kBN = kB * kN;        // 8192
constexpr int kQKV = 3 * kNH * kDH; // 1536

typedef __attribute__((ext_vector_type(8))) short bf16x8;
typedef __attribute__((ext_vector_type(4))) float f32x4;

#define LOG2E 1.4426950408889634f

__device__ __forceinline__ unsigned short f2bf(float f) {
    unsigned int u = __float_as_uint(f);
    unsigned int r = (u + 0x7FFFu + ((u >> 16) & 1u)) >> 16;   // RNE
    return (unsigned short)r;
}

__device__ __forceinline__ float exp2_fast(float x) {
#if __has_builtin(__builtin_amdgcn_exp2f)
    return __builtin_amdgcn_exp2f(x);
#else
    return exp2f(x);
#endif
}

// ---------------- K0a: elementwise fp32 -> bf16 ----------------------------
__global__ __launch_bounds__(256) void convert_x(
    const float* __restrict__ in, unsigned short* __restrict__ out)
{
    const int i = blockIdx.x * 256 + threadIdx.x;
    float4 v = reinterpret_cast<const float4*>(in)[i];
    ushort4 o;
    o.x = f2bf(v.x); o.y = f2bf(v.y); o.z = f2bf(v.z); o.w = f2bf(v.w);
    reinterpret_cast<ushort4*>(out)[i] = o;
}

// ---------------- K0b: transpose + convert: in[R][C] fp32 -> out[C][R] bf16 -
__global__ __launch_bounds__(256) void transpose_convert(
    const float* __restrict__ in, unsigned short* __restrict__ out, int R, int C)
{
    __shared__ float T[64][65];
    const int tid = threadIdx.x;
    const int c0 = blockIdx.x * 64, r0 = blockIdx.y * 64;
    #pragma unroll
    for (int p = 0; p < 4; p++) {
        const int r = (tid >> 4) + p * 16, c = (tid & 15) * 4;
        float4 v = *reinterpret_cast<const float4*>(in + (size_t)(r0 + r) * C + c0 + c);
        T[r][c + 0] = v.x; T[r][c + 1] = v.y; T[r][c + 2] = v.z; T[r][c + 3] = v.w;
    }
    __syncthreads();
    #pragma unroll
    for (int p = 0; p < 4; p++) {
        const int c = (tid >> 4) + p * 16, r4 = (tid & 15) * 4;
        ushort4 w;
        w.x = f2bf(T[r4 + 0][c]); w.y = f2bf(T[r4 + 1][c]);
        w.z = f2bf(T[r4 + 2][c]); w.w = f2bf(T[r4 + 3][c]);
        *reinterpret_cast<ushort4*>(out + (size_t)(c0 + c) * R + r0 + r4) = w;
    }
}

// ---------------- K1: QKV MFMA GEMM + bf16 scatter --------------------------
__global__ __launch_bounds__(256) void qkv_mfma(
    const unsigned short* __restrict__ A,    // xb [8192][512]
    const unsigned short* __restrict__ Bt,   // Wqt [1536][512]
    const float* __restrict__ bias,          // [1536]
    unsigned short* __restrict__ q_ws,       // [bh][n][32]
    unsigned short* __restrict__ k_ws,       // [bh][n][32]
    unsigned short* __restrict__ v_ws)       // [bh][32][n]  (transposed!)
{
    __shared__ unsigned short As[128 * 72];
    __shared__ unsigned short Bs[128 * 72];
    const int tid = threadIdx.x;
    const int wave = tid >> 6, lane = tid & 63;
    const int col = lane & 15, hi = lane >> 4;
    const int wr = wave >> 1, wc = wave & 1;
    const int m0 = blockIdx.x * 128, n0 = blockIdx.y * 128;

    f32x4 acc[4][4] = {};
    for (int k0 = 0; k0 < kC; k0 += 64) {
        #pragma unroll
        for (int i = 0; i < 4; i++) {
            const int ch = i * 256 + tid, row = ch >> 3, cc = (ch & 7) * 8;
            *reinterpret_cast<bf16x8*>(&As[row * 72 + cc]) =
                *reinterpret_cast<const bf16x8*>(A + (size_t)(m0 + row) * kC + k0 + cc);
            *reinterpret_cast<bf16x8*>(&Bs[row * 72 + cc]) =
                *reinterpret_cast<const bf16x8*>(Bt + (size_t)(n0 + row) * kC + k0 + cc);
        }
        __syncthreads();
        #pragma unroll
        for (int kk = 0; kk < 2; kk++) {
            bf16x8 af[4], bfr[4];
            #pragma unroll
            for (int mt = 0; mt < 4; mt++)
                af[mt] = *reinterpret_cast<const bf16x8*>(
                    &As[(wr * 64 + mt * 16 + col) * 72 + kk * 32 + 8 * hi]);
            #pragma unroll
            for (int nt = 0; nt < 4; nt++)
                bfr[nt] = *reinterpret_cast<const bf16x8*>(
                    &Bs[(wc * 64 + nt * 16 + col) * 72 + kk * 32 + 8 * hi]);
            #pragma unroll
            for (int mt = 0; mt < 4; mt++)
                #pragma unroll
                for (int nt = 0; nt < 4; nt++)
                    acc[mt][nt] = __builtin_amdgcn_mfma_f32_16x16x32_bf16(
                        af[mt], bfr[nt], acc[mt][nt], 0, 0, 0);
        }
        __syncthreads();
    }

    // Q scale = 1/sqrt(32) * log2(e): folds softmax scale AND exp2-domain.
    const float scale = 0.25503238645263514f;
    #pragma unroll
    for (int nt = 0; nt < 4; nt++) {
        const int n = n0 + wc * 64 + nt * 16 + col;
        const int head = n / 96;
        const int r = n - head * 96;
        const float bv = bias[n];
        #pragma unroll
        for (int mt = 0; mt < 4; mt++)
            #pragma unroll
            for (int reg = 0; reg < 4; reg++) {
                const int m = m0 + wr * 64 + mt * 16 + 4 * hi + reg;
                const int bb = m >> 10, np = m & 1023;
                const float v = acc[mt][nt][reg] + bv;
                const size_t bh = (size_t)(bb * kNH + head);
                if (r < 32)
                    q_ws[(bh * kN + np) * kDH + r] = f2bf(v * scale);
                else if (r < 64)
                    k_ws[(bh * kN + np) * kDH + r - 32] = f2bf(v);
                else
                    v_ws[(bh * kDH + (r - 64)) * kN + np] = f2bf(v);   // transposed
            }
    }
}

// ---------------- K2: swapped-QK^T attention, verified PV -------------------
// grid (N/64, 128): h = y>>3, b = y&7. Wave w owns q-rows [bx*64+w*16, +16).
// QK^T: lane holds S[key=16t+4hi+reg][q=col]; softmax in-lane over 16 keys +
// shfl_xor 16/32 across hi-partners. P staged to per-wave LDS [q=col][key],
// then PV = R3's verified 16x16x32 block: O[q=4hi+reg][d=col | 16+col].
__global__ __launch_bounds__(256) void attn_kernel(
    const unsigned short* __restrict__ q_ws,
    const unsigned short* __restrict__ k_ws,
    const unsigned short* __restrict__ v_ws,   // [bh][32][1024]
    const float* __restrict__ rel,
    unsigned short* __restrict__ aout)          // [8192][512] bf16
{
    __shared__ unsigned short Ks[64 * 72];      // [key][d], stride 72
    __shared__ unsigned short Vt[32 * 72];      // [d][key], stride 72
    __shared__ unsigned short Pl[4][16 * 72];   // per-wave [q][key]

    const int tid = threadIdx.x;
    const int wave = tid >> 6, lane = tid & 63;
    const int col = lane & 15, hi = lane >> 4;
    const int h = blockIdx.y >> 3, b = blockIdx.y & 7;
    const int bh = b * kNH + h;
    const int r0 = blockIdx.x * 64 + wave * 16;

    // Q B-fragment (n = q = col), resident all loop
    const bf16x8 q_frag = *reinterpret_cast<const bf16x8*>(
        q_ws + ((size_t)bh * kN + r0 + col) * kDH + 8 * hi);

    const unsigned short* kb  = k_ws + (size_t)bh * kN * kDH;
    const unsigned short* vtb = v_ws + (size_t)bh * kDH * kN;
    const float* relq = rel + ((size_t)h * kN + r0 + col) * kN;   // lane's q-row

    f32x4 o0 = {0.f, 0.f, 0.f, 0.f};   // O[q=4hi+reg][d=col]
    f32x4 o1 = {0.f, 0.f, 0.f, 0.f};   // O[q=4hi+reg][d=16+col]
    float m2 = -1e30f, l = 0.f;        // stats for q=col (log2 domain)

    const int kr = tid >> 2, kd8 = (tid & 3) * 8;   // K stage: [64][32]
    const int vr = tid >> 3, vk8 = (tid & 7) * 8;   // Vt stage: [32][64]

    bf16x8 kreg = *reinterpret_cast<const bf16x8*>(kb + (size_t)kr * kDH + kd8);
    bf16x8 vreg = *reinterpret_cast<const bf16x8*>(vtb + (size_t)vr * kN + vk8);

    for (int c0 = 0; c0 < kN; c0 += 64) {
        *reinterpret_cast<bf16x8*>(&Ks[kr * 72 + kd8]) = kreg;
        *reinterpret_cast<bf16x8*>(&Vt[vr * 72 + vk8]) = vreg;
        __syncthreads();
        if (c0 + 64 < kN) {   // prefetch next tile into regs
            kreg = *reinterpret_cast<const bf16x8*>(kb + (size_t)(c0 + 64 + kr) * kDH + kd8);
            vreg = *reinterpret_cast<const bf16x8*>(vtb + (size_t)vr * kN + c0 + 64 + vk8);
        }

        // ---- S = K * Q^T : lane holds S[key=16t+4hi+reg][q=col], log2 units
        f32x4 s[4];
        #pragma unroll
        for (int t = 0; t < 4; t++) {
            const bf16x8 kf = *reinterpret_cast<const bf16x8*>(
                &Ks[(t * 16 + col) * 72 + 8 * hi]);
            const f32x4 z = {0.f, 0.f, 0.f, 0.f};
            s[t] = __builtin_amdgcn_mfma_f32_16x16x32_bf16(kf, q_frag, z, 0, 0, 0);
        }

        // ---- + bias*log2e : k-contiguous dwordx4 per t ----
        #pragma unroll
        for (int t = 0; t < 4; t++) {
            const f32x4 b4 = *reinterpret_cast<const f32x4*>(relq + c0 + t * 16 + 4 * hi);
            #pragma unroll
            for (int r = 0; r < 4; r++)
                s[t][r] = fmaf(b4[r], LOG2E, s[t][r]);
        }

        // ---- online softmax over keys (16 in-lane + xor16/32) ----
        float cm = s[0][0];
        #pragma unroll
        for (int t = 0; t < 4; t++)
            #pragma unroll
            for (int r = 0; r < 4; r++)
                cm = fmaxf(cm, s[t][r]);
        cm = fmaxf(cm, __shfl_xor(cm, 16));
        cm = fmaxf(cm, __shfl_xor(cm, 32));
        const float nm = fmaxf(m2, cm);
        const float corr = exp2_fast(m2 - nm);
        m2 = nm;

        float ps = 0.f;
        #pragma unroll
        for (int t = 0; t < 4; t++)
            #pragma unroll
            for (int r = 0; r < 4; r++) {
                s[t][r] = exp2_fast(s[t][r] - nm);
                ps += s[t][r];
            }
        ps += __shfl_xor(ps, 16);
        ps += __shfl_xor(ps, 32);
        l = l * corr + ps;

        // ---- rescale O by corr of ITS q-rows (q = 4hi+reg, via shfl) ----
        #pragma unroll
        for (int r = 0; r < 4; r++) {
            const float cq = __shfl(corr, 4 * hi + r);
            o0[r] *= cq;
            o1[r] *= cq;
        }

        // ---- P -> bf16 -> per-wave LDS [q=col][key] (8B ushort4 stores) ----
        unsigned short* pw = &Pl[wave][col * 72];
        #pragma unroll
        for (int t = 0; t < 4; t++) {
            ushort4 pk;
            pk.x = f2bf(s[t][0]); pk.y = f2bf(s[t][1]);
            pk.z = f2bf(s[t][2]); pk.w = f2bf(s[t][3]);
            *reinterpret_cast<ushort4*>(pw + t * 16 + 4 * hi) = pk;
        }
        // same-wave LDS write->read: lgkmcnt ordering, no barrier needed

        // ---- PV (R3-verified): O[q][d] += P[q][k] * V^T[d][k] ----
        #pragma unroll
        for (int half = 0; half < 2; half++) {
            const bf16x8 pa = *reinterpret_cast<const bf16x8*>(
                &Pl[wave][col * 72 + half * 32 + 8 * hi]);
            const bf16x8 v0 = *reinterpret_cast<const bf16x8*>(
                &Vt[col * 72 + half * 32 + 8 * hi]);
            const bf16x8 v1 = *reinterpret_cast<const bf16x8*>(
                &Vt[(16 + col) * 72 + half * 32 + 8 * hi]);
            o0 = __builtin_amdgcn_mfma_f32_16x16x32_bf16(pa, v0, o0, 0, 0, 0);
            o1 = __builtin_amdgcn_mfma_f32_16x16x32_bf16(pa, v1, o1, 0, 0, 0);
        }
        __syncthreads();   // protect Ks/Vt before next chunk's stage
    }

    // ---- epilogue: O rows q = r0+4hi+reg; l broadcast from lane 4hi+reg ----
    #pragma unroll
    for (int r = 0; r < 4; r++) {
        const float inv = 1.0f / __shfl(l, 4 * hi + r);
        unsigned short* orow = aout + ((size_t)b * kN + r0 + 4 * hi + r) * kC + h * kDH;
        orow[col]      = f2bf(o0[r] * inv);
        orow[16 + col] = f2bf(o1[r] * inv);
    }
}

// ---------------- K3: output projection MFMA GEMM ---------------------------
__global__ __launch_bounds__(256) void proj_mfma(
    const unsigned short* __restrict__ A,    // a_ws bf16 [8192][512]
    const unsigned short* __restrict__ Bt,   // Wpt bf16 [512][512]
    const float* __restrict__ bias,          // [512]
    float* __restrict__ out)                 // [8192][512] fp32
{
    __shared__ unsigned short As[128 * 72];
    __shared__ unsigned short Bs[128 * 72];
    const int tid = threadIdx.x;
    const int wave = tid >> 6, lane = tid & 63;
    const int col = lane & 15, hi = lane >> 4;
    const int wr = wave >> 1, wc = wave & 1;
    const int m0 = blockIdx.x * 128, n0 = blockIdx.y * 128;

    f32x4 acc[4][4] = {};
    for (int k0 = 0; k0 < kC; k0 += 64) {
        #pragma unroll
        for (int i = 0; i < 4; i++) {
            const int ch = i * 256 + tid, row = ch >> 3, cc = (ch & 7) * 8;
            *reinterpret_cast<bf16x8*>(&As[row * 72 + cc]) =
                *reinterpret_cast<const bf16x8*>(A + (size_t)(m0 + row) * kC + k0 + cc);
            *reinterpret_cast<bf16x8*>(&Bs[row * 72 + cc]) =
                *reinterpret_cast<const bf16x8*>(Bt + (size_t)(n0 + row) * kC + k0 + cc);
        }
        __syncthreads();
        #pragma unroll
        for (int kk = 0; kk < 2; kk++) {
            bf16x8 af[4], bfr[4];
            #pragma unroll
            for (int mt = 0; mt < 4; mt++)
                af[mt] = *reinterpret_cast<const bf16x8*>(
                    &As[(wr * 64 + mt * 16 + col) * 72 + kk * 32 + 8 * hi]);
            #pragma unroll
            for (int nt = 0; nt < 4; nt++)
                bfr[nt] = *reinterpret_cast<const bf16x8*>(
                    &Bs[(wc * 64 + nt * 16 + col) * 72 + kk * 32 + 8 * hi]);
            #pragma unroll
            for (int mt = 0; mt < 4; mt++)
                #pragma unroll
                for (int nt = 0; nt < 4; nt++)
                    acc[mt][nt] = __builtin_amdgcn_mfma_f32_16x16x32_bf16(
                        af[mt], bfr[nt], acc[mt][nt], 0, 0, 0);
        }
        __syncthreads();
    }

    #pragma unroll
    for (int nt = 0; nt < 4; nt++) {
        const int n = n0 + wc * 64 + nt * 16 + col;
        const float bv = bias[n];
        #pragma unroll
        for (int mt = 0; mt < 4; mt++)
            #pragma unroll
            for (int reg = 0; reg < 4; reg++) {
                const int m = m0 + wr * 64 + mt * 16 + 4 * hi + reg;
                out[(size_t)m * kC + n] = acc[mt][nt][reg] + bv;
            }
    }
}

// ---------------------------------------------------------------------------
extern "C" void kernel_launch(void* const* d_in, const int* in_sizes, int n_in,
                              void* d_out, int out_size, void* d_ws, size_t ws_size,
                              hipStream_t stream) {
    const float* x     = (const float*)d_in[0];
    const float* rel   = (const float*)d_in[1];
    const float* Wqkv  = (const float*)d_in[2];
    const float* bqkv  = (const float*)d_in[3];
    const float* Wproj = (const float*)d_in[4];
    const float* bproj = (const float*)d_in[5];
    float* out = (float*)d_out;

    unsigned short* ws = (unsigned short*)d_ws;
    const size_t qkv_elems = (size_t)kB * kNH * kN * kDH;   // 4M
    unsigned short* q_ws = ws;                    ws += qkv_elems;
    unsigned short* k_ws = ws;                    ws += qkv_elems;
    unsigned short* v_ws = ws;                    ws += qkv_elems;
    unsigned short* a_ws = ws;                    ws += (size_t)kBN * kC;
    unsigned short* xb   = ws;                    ws += (size_t)kBN * kC;
    unsigned short* Wqt  = ws;                    ws += (size_t)kQKV * kC;
    unsigned short* Wpt  = ws;                    ws += (size_t)kC * kC;

    convert_x<<<dim3(kBN * kC / 4 / 256), 256, 0, stream>>>(x, xb);
    transpose_convert<<<dim3(kQKV / 64, kC / 64), 256, 0, stream>>>(Wqkv, Wqt, kC, kQKV);
    transpose_convert<<<dim3(kC / 64, kC / 64), 256, 0, stream>>>(Wproj, Wpt, kC, kC);

    qkv_mfma<<<dim3(kBN / 128, kQKV / 128), 256, 0, stream>>>(xb, Wqt, bqkv, q_ws, k_ws, v_ws);
    attn_kernel<<<dim3(kN / 64, kB * kNH), 256, 0, stream>>>(q_ws, k_ws, v_ws, rel, a_ws);
    proj_mfma<<<dim3(kBN / 128, kC / 128), 256, 0, stream>>>(a_ws, Wpt, bproj, out);
}